// Round 13
// baseline (177.091 us; speedup 1.0000x reference)
//
#include <hip/hip_runtime.h>

// ---------------------------------------------------------------------------
// v12: v9 config restored (best measured 171.2; attn = reg-staged 1024-block
//   LPT) + Xh roundtrip eliminated: QKV gemm stages A directly from fp32 X
//   with in-register cvt (RTN, same numerics as old xcvt) + ds_write_b128
//   into the SAME linear+swizzled As layout (read side untouched). prep is
//   now wtrans-only (1024 blocks). O gemm keeps f16 gload_lds A (ctx).
// Pipeline: wtrans -> QKV gemm (fp32 A, Q prescaled, V transposed)
//           -> flash attn -> O gemm (128x64 tiles).
// gemmT: 32x32x16, BK=64, rule-#21 swizzle (v9-measured: conflicts gone).
// attn: 32x32x16 MFMA; 4 waves = 2(q-half) x 2(kv-half); S^T output regs ARE
//   the PV A-frags (P in-register, v_cvt_pkrtz); raw v_exp_f32; l via fdot2.
// 32x32x16 layouts (HW-validated): A/B m|n=lane&31, k=(lane>>5)*8+j;
//   C/D col=lane&31, row=(reg&3)+8*(reg>>2)+4*(lane>>5).
// ---------------------------------------------------------------------------

typedef _Float16 f16x8 __attribute__((ext_vector_type(8)));
typedef _Float16 f16x4 __attribute__((ext_vector_type(4)));
typedef __fp16 h16x2 __attribute__((ext_vector_type(2)));  // cvt_pkrtz ret type
typedef float f32x4 __attribute__((ext_vector_type(4)));
typedef float f32x16 __attribute__((ext_vector_type(16)));

#define GLD_LDS16(g, l)                                                        \
  __builtin_amdgcn_global_load_lds(                                            \
      (__attribute__((address_space(1))) const unsigned int*)(g),              \
      (__attribute__((address_space(3))) unsigned int*)(l), 16, 0, 0)

static constexpr int Sdim = 2048;
static constexpr int Ddim = 1024;
static constexpr int NH = 16;
static constexpr int DH = 64;
static constexpr int Mrows = 4096;  // B*S

// Q prescale: 1/sqrt(64) * log2(e), so P = exp2(S') natively.
static constexpr float QSCALE = 0.125f * 1.44269504f;

// ------------------- prep: weight fp32 [K,N] -> fp16 [N,K] -----------------
struct PrepArgs {
  const float *s0, *s1, *s2, *s3;
  _Float16 *d0, *d1, *d2, *d3;
};

__global__ __launch_bounds__(256) void prep(PrepArgs a) {
  __shared__ _Float16 L[64 * 72];
  const int id = blockIdx.x, t = threadIdx.x;
  const int z = id >> 8;
  const float* src = z == 0 ? a.s0 : z == 1 ? a.s1 : z == 2 ? a.s2 : a.s3;
  _Float16* dst = z == 0 ? a.d0 : z == 1 ? a.d1 : z == 2 ? a.d2 : a.d3;
  const int k0 = (id & 15) * 64, n0 = ((id >> 4) & 15) * 64;
#pragma unroll
  for (int i = 0; i < 4; ++i) {
    int c = i * 256 + t;  // 1024 chunks of 4 floats
    int row = c >> 4, cc = c & 15;
    float4 f = *(const float4*)&src[(size_t)(k0 + row) * Ddim + n0 + cc * 4];
    L[(cc * 4 + 0) * 72 + row] = (_Float16)f.x;
    L[(cc * 4 + 1) * 72 + row] = (_Float16)f.y;
    L[(cc * 4 + 2) * 72 + row] = (_Float16)f.z;
    L[(cc * 4 + 3) * 72 + row] = (_Float16)f.w;
  }
  __syncthreads();
#pragma unroll
  for (int i = 0; i < 2; ++i) {
    int c = i * 256 + t;  // 512 chunks of 8 halves
    int n = c >> 3, cc = c & 7;
    *(uint4*)&dst[(size_t)(n0 + n) * Ddim + k0 + cc * 8] =
        *(const uint4*)&L[n * 72 + cc * 8];
  }
}

// --------------- 128xBN GEMM (32x32x16, BK=64, swizzled LDS) ---------------
// LDS tile rows are 64 halves (128B). Slot s (16B) of row r holds global
// k-slot s^(r&7) (inverse-swizzled source); reads XOR the same term.
// MODE 0 (BN=128): A = fp32 X, reg-staged with in-register cvt (RTN) +
//   ds_write_b128 (same As layout); B f16 via gload_lds. +bias -> fp16;
//   z==0 Q (xQSCALE); z==1 K; z==2 V^T.
// MODE 1 (BN=64): A = f16 ctx via gload_lds; +bias -> fp32 d_out; 512 blocks.
struct GemmArgs {
  const void* A;  // MODE0: const float*  MODE1: const _Float16*
  const _Float16 *Bt0, *Bt1, *Bt2;
  const float *b0, *b1, *b2;
  void *o0, *o1, *o2;
};

template <int MODE, int BN>
__global__ __launch_bounds__(256) void gemmT(GemmArgs g) {
  constexpr int K = 1024;
  constexpr int BK = 64;
  constexpr int WN = BN / 2;       // per-wave n extent
  constexpr int NI = WN / 32;      // 32-wide n frags per wave
  constexpr int BCH = BN * 8;      // B chunk count (16B each)
  __shared__ _Float16 As[128 * BK];
  __shared__ _Float16 Bs[BN * BK];
  const int z = blockIdx.z;
  const _Float16* Bt = z == 0 ? g.Bt0 : z == 1 ? g.Bt1 : g.Bt2;
  const float* bias = z == 0 ? g.b0 : z == 1 ? g.b1 : g.b2;
  void* out = z == 0 ? g.o0 : z == 1 ? g.o1 : g.o2;
  const int m0 = blockIdx.x * 128, n0 = blockIdx.y * BN;
  const int t = threadIdx.x, lane = t & 63, wv = t >> 6;
  const int wm = wv >> 1, wn = wv & 1;
  const int n31 = lane & 31, h5 = lane >> 5, h8 = h5 * 8;

  // staging chunk c -> row c>>3, LDS slot c&7 (linear, c*16B); global k-slot
  // = (c&7) ^ (row&7)  [inverse swizzle at the source, rule #21].
  const float* gaf[4];      // MODE0: fp32 A source
  const _Float16* ga[4];    // MODE1: f16 A source
  char* lA[4];              // MODE1: wave-uniform gload_lds dest
  char* lAw[4];             // MODE0: per-thread ds_write dest
  const _Float16* gb[4];
  char* lB[4];
#pragma unroll
  for (int i = 0; i < 4; ++i) {
    const int c = i * 256 + t, row = c >> 3, slot = (c & 7) ^ (row & 7);
    if constexpr (MODE == 0) {
      gaf[i] = (const float*)g.A + (size_t)(m0 + row) * K + slot * 8;
      lAw[i] = (char*)As + (size_t)c * 16;
    } else {
      ga[i] = (const _Float16*)g.A + (size_t)(m0 + row) * K + slot * 8;
      lA[i] = (char*)As + (i * 256 + wv * 64) * 16;
    }
  }
#pragma unroll
  for (int i = 0; i < BCH / 256; ++i) {
    const int c = i * 256 + t, row = c >> 3, slot = (c & 7) ^ (row & 7);
    gb[i] = Bt + (size_t)(n0 + row) * K + slot * 8;
    lB[i] = (char*)Bs + (i * 256 + wv * 64) * 16;
  }
  const int rsw = (n31 & 7) << 3;  // read swizzle (all frag rows have &7==n31&7)

  f32x16 acc[2][NI] = {};
  for (int kt = 0; kt < K; kt += BK) {
    if constexpr (MODE == 0) {
      float4 fa[4][2];
#pragma unroll
      for (int i = 0; i < 4; ++i) {
        fa[i][0] = *(const float4*)(gaf[i] + kt);
        fa[i][1] = *(const float4*)(gaf[i] + kt + 4);
      }
#pragma unroll
      for (int i = 0; i < BCH / 256; ++i) GLD_LDS16(gb[i] + kt, lB[i]);
#pragma unroll
      for (int i = 0; i < 4; ++i) {
        alignas(16) _Float16 h[8] = {
            (_Float16)fa[i][0].x, (_Float16)fa[i][0].y, (_Float16)fa[i][0].z,
            (_Float16)fa[i][0].w, (_Float16)fa[i][1].x, (_Float16)fa[i][1].y,
            (_Float16)fa[i][1].z, (_Float16)fa[i][1].w};
        *(uint4*)lAw[i] = *(const uint4*)h;
      }
    } else {
#pragma unroll
      for (int i = 0; i < 4; ++i) GLD_LDS16(ga[i] + kt, lA[i]);
#pragma unroll
      for (int i = 0; i < BCH / 256; ++i) GLD_LDS16(gb[i] + kt, lB[i]);
    }
    __syncthreads();
#pragma unroll
    for (int ks = 0; ks < 4; ++ks) {
      const int kc = (ks * 16 + h8) ^ rsw;
      f16x8 a0 = *(const f16x8*)&As[(wm * 64 + n31) * BK + kc];
      f16x8 a1 = *(const f16x8*)&As[(wm * 64 + 32 + n31) * BK + kc];
#pragma unroll
      for (int ni = 0; ni < NI; ++ni) {
        f16x8 bf = *(const f16x8*)&Bs[(wn * WN + ni * 32 + n31) * BK + kc];
        acc[0][ni] =
            __builtin_amdgcn_mfma_f32_32x32x16_f16(a0, bf, acc[0][ni], 0, 0, 0);
        acc[1][ni] =
            __builtin_amdgcn_mfma_f32_32x32x16_f16(a1, bf, acc[1][ni], 0, 0, 0);
      }
    }
    __syncthreads();
  }

  const float scale = (MODE == 0 && z == 0) ? QSCALE : 1.0f;
  float bv[NI];
#pragma unroll
  for (int ni = 0; ni < NI; ++ni) bv[ni] = bias[n0 + wn * WN + ni * 32 + n31];
#pragma unroll
  for (int mi = 0; mi < 2; ++mi) {
#pragma unroll
    for (int ni = 0; ni < NI; ++ni) {
      const int n = n0 + wn * WN + ni * 32 + n31;
      if (MODE == 0 && z == 2) {
        // V^T store: rows (reg&3) consecutive in s -> uint2 of 4 halves
        const int b = (m0 >> 11), h = n >> 6, dh = n & 63;
#pragma unroll
        for (int hi = 0; hi < 4; ++hi) {
          alignas(8) _Float16 h4[4];
#pragma unroll
          for (int j = 0; j < 4; ++j)
            h4[j] = (_Float16)(acc[mi][ni][hi * 4 + j] + bv[ni]);
          const int m = m0 + wm * 64 + mi * 32 + 8 * hi + 4 * h5;
          const int s = m & 2047;
          *(uint2*)&(
              (_Float16*)out)[((size_t)(b * NH + h) * DH + dh) * Sdim + s] =
              *(const uint2*)h4;
        }
      } else {
#pragma unroll
        for (int rr = 0; rr < 16; ++rr) {
          const int m =
              m0 + wm * 64 + mi * 32 + (rr & 3) + 8 * (rr >> 2) + 4 * h5;
          const float v = (acc[mi][ni][rr] + bv[ni]) * scale;
          if (MODE == 0) {
            const int b = m >> 11, s = m & 2047, h = n >> 6, dh = n & 63;
            ((_Float16*)out)[(((size_t)(b * NH + h) * Sdim + s) << 6) + dh] =
                (_Float16)v;
          } else {
            ((float*)out)[(size_t)m * Ddim + n] = v;
          }
        }
      }
    }
  }
}

// ------------------------- flash attention (v9) ----------------------------
// 1024 blocks x 256 thr; block = one 64-q tile; LPT descending; bh XCD-local
// (4 blocks/CU resident -> TLP hides the serial tile chain). Reg-staged K/V
// with prefetch-before-barrier + ds_write double-buffer (v9 = best measured).
// K rows LDS-permuted (swap bits 2,3) so S^T C/D regs feed PV A-frags
// directly (P fully in-register). LDS [64][64] tiles, XOR-swizzle (row&7)<<3.
__global__ __launch_bounds__(256) void attn(const _Float16* __restrict__ Q,
                                            const _Float16* __restrict__ Kk,
                                            const _Float16* __restrict__ Vt,
                                            _Float16* __restrict__ ctx) {
  __shared__ _Float16 Ks[2][64 * 64], Vs[2][64 * 64];
  const int id = blockIdx.x, xcd = id & 7, slot = id >> 3;
  const int qt = 31 - (slot >> 2);           // descending work (LPT)
  const int bh = ((slot & 3) << 3) | xcd;    // 4 bh per xcd
  const int q0 = qt * 64;
  const int t = threadIdx.x, lane = t & 63, wv = t >> 6;
  const int qh = wv & 1, kvh = wv >> 1;
  const int n31 = lane & 31, h5 = lane >> 5, h8 = h5 * 8;
  const int b = bh >> 4, h = bh & 15;
  const _Float16* Kg = Kk + (size_t)bh * Sdim * DH;
  const _Float16* Vg = Vt + (size_t)bh * DH * Sdim;  // [64 dh, S]

  const int qg = q0 + qh * 32 + n31;  // lane's q column (S^T col)
  const _Float16* Qrow = Q + ((size_t)bh * Sdim + qg) * DH;
  f16x8 aq[4];
#pragma unroll
  for (int ks = 0; ks < 4; ++ks) aq[ks] = *(const f16x8*)(Qrow + ks * 16 + h8);

  const int ntiles = qt + 1;
  // staging: thread covers rows sr, sr+32 (16B chunk each) for K and V
  const int sr = t >> 3, sr2 = sr + 32, sc = (t & 7) * 8;
  // K rows permuted: swap bits 2,3 (kv-contraction relabel; V cols natural)
  const int kr = (sr & 51) | ((sr & 4) << 1) | ((sr & 8) >> 1);
  const int kr2 = (sr2 & 51) | ((sr2 & 4) << 1) | ((sr2 & 8) >> 1);
  const int kc = sc ^ ((kr & 7) << 3), kc2 = sc ^ ((kr2 & 7) << 3);
  const int vc = sc ^ ((sr & 7) << 3), vc2 = sc ^ ((sr2 & 7) << 3);

  f32x16 oacc0 = {}, oacc1 = {};
  float l_i = 0.f;
  const h16x2 one2 = {(__fp16)1.0f, (__fp16)1.0f};

  // prologue: stage tile 0 into buf 0
  uint4 ka = *(const uint4*)&Kg[(size_t)sr * DH + sc];
  uint4 kb = *(const uint4*)&Kg[(size_t)sr2 * DH + sc];
  uint4 va = *(const uint4*)&Vg[(size_t)sr * Sdim + sc];
  uint4 vb = *(const uint4*)&Vg[(size_t)sr2 * Sdim + sc];
  *(uint4*)&Ks[0][kr * 64 + kc] = ka;
  *(uint4*)&Ks[0][kr2 * 64 + kc2] = kb;
  *(uint4*)&Vs[0][sr * 64 + vc] = va;
  *(uint4*)&Vs[0][sr2 * 64 + vc2] = vb;

  const int prow = kvh * 32 + n31;            // Ks read row for S-phase
  const int pb = prow * 64, psw = (prow & 7) << 3;
  const int vsw = (n31 & 7) << 3;             // Vs read swizzle

  for (int it = 0; it < ntiles; ++it) {
    const int cur = it & 1;
    if (it + 1 < ntiles) {  // prefetch next tile into regs (T14: issue early)
      const int kvn = (it + 1) * 64;
      ka = *(const uint4*)&Kg[(size_t)(kvn + sr) * DH + sc];
      kb = *(const uint4*)&Kg[(size_t)(kvn + sr2) * DH + sc];
      va = *(const uint4*)&Vg[(size_t)sr * Sdim + kvn + sc];
      vb = *(const uint4*)&Vg[(size_t)sr2 * Sdim + kvn + sc];
    }
    __syncthreads();  // buf[cur] fully staged

    // S^T = K Q^T over the wave's 32-kv half (single acc chain)
    f32x16 sacc = {};
    __builtin_amdgcn_s_setprio(1);
#pragma unroll
    for (int ks = 0; ks < 4; ++ks) {
      f16x8 ak = *(const f16x8*)&Ks[cur][pb + ((ks * 16 + h8) ^ psw)];
      sacc = __builtin_amdgcn_mfma_f32_32x32x16_f16(ak, aq[ks], sacc, 0, 0, 0);
    }
    __builtin_amdgcn_s_setprio(0);

    // mask (diag tile only; wave-uniform branch)
    const int kvb = it * 64;
    if (it == ntiles - 1) {
#pragma unroll
      for (int i = 0; i < 16; ++i) {
        const int kvgl = kvb + kvh * 32 + (i & 7) + h8 + 16 * (i >> 3);
        if (kvgl > qg) sacc[i] = -1e30f;
      }
    }
    // P = exp2 (raw v_exp_f32), pack to f16 pairs, l via v_dot2_f32_f16
    union U { f16x8 v8; h16x2 v2[4]; } u0, u1;
#pragma unroll
    for (int i = 0; i < 4; ++i) {
      const float p0 = __builtin_amdgcn_exp2f(sacc[2 * i]);
      const float p1 = __builtin_amdgcn_exp2f(sacc[2 * i + 1]);
      u0.v2[i] = __builtin_amdgcn_cvt_pkrtz(p0, p1);
      l_i = __builtin_amdgcn_fdot2(u0.v2[i], one2, l_i, false);
    }
#pragma unroll
    for (int i = 0; i < 4; ++i) {
      const float p0 = __builtin_amdgcn_exp2f(sacc[8 + 2 * i]);
      const float p1 = __builtin_amdgcn_exp2f(sacc[9 + 2 * i]);
      u1.v2[i] = __builtin_amdgcn_cvt_pkrtz(p0, p1);
      l_i = __builtin_amdgcn_fdot2(u1.v2[i], one2, l_i, false);
    }

    // O += P V over the wave's kv half: B = V^T rows (n = dh)
    __builtin_amdgcn_s_setprio(1);
#pragma unroll
    for (int ks = 0; ks < 2; ++ks) {
      const f16x8 ap = ks ? u1.v8 : u0.v8;
      const int col = kvh * 32 + ks * 16 + h8;
      f16x8 bv0 = *(const f16x8*)&Vs[cur][n31 * 64 + (col ^ vsw)];
      f16x8 bv1 = *(const f16x8*)&Vs[cur][(32 + n31) * 64 + (col ^ vsw)];
      oacc0 = __builtin_amdgcn_mfma_f32_32x32x16_f16(ap, bv0, oacc0, 0, 0, 0);
      oacc1 = __builtin_amdgcn_mfma_f32_32x32x16_f16(ap, bv1, oacc1, 0, 0, 0);
    }
    __builtin_amdgcn_s_setprio(0);

    if (it + 1 < ntiles) {  // write prefetched regs into other buffer
      const int nxt = cur ^ 1;
      *(uint4*)&Ks[nxt][kr * 64 + kc] = ka;
      *(uint4*)&Ks[nxt][kr2 * 64 + kc2] = kb;
      *(uint4*)&Vs[nxt][sr * 64 + vc] = va;
      *(uint4*)&Vs[nxt][sr2 * 64 + vc2] = vb;
    }
  }

  // ---- cross-wave kv-half reduction (once per block) ----
  l_i += __shfl_xor(l_i, 32, 64);  // full sum over this wave's kv half
  __syncthreads();                 // all KV LDS reads done; reuse as scratch
  float* obuf = (float*)&Ks[0][0] + qh * (64 * 32);  // 8KB per q-half
  float* lbuf = (float*)&Vs[0][0] + qh * 64;
  union V16 { f32x16 v; f32x4 q[4]; };
  if (kvh == 1) {
    V16 a, c;
    a.v = oacc0;
    c.v = oacc1;
#pragma unroll
    for (int k = 0; k < 4; ++k) {
      *(f32x4*)&obuf[lane * 32 + ((k ^ (lane & 7)) << 2)] = a.q[k];
      *(f32x4*)&obuf[lane * 32 + (((k + 4) ^ (lane & 7)) << 2)] = c.q[k];
    }
    lbuf[lane] = l_i;
  }
  __syncthreads();
  if (kvh == 0) {
    V16 a, c;
#pragma unroll
    for (int k = 0; k < 4; ++k) {
      a.q[k] = *(const f32x4*)&obuf[lane * 32 + ((k ^ (lane & 7)) << 2)];
      c.q[k] = *(const f32x4*)&obuf[lane * 32 + (((k + 4) ^ (lane & 7)) << 2)];
    }
    oacc0 += a.v;
    oacc1 += c.v;
    l_i += lbuf[lane];
    // epilogue: row q = (rr&3)+8*(rr>>2)+4*h5; col dh = n31 (+32)
#pragma unroll
    for (int rr = 0; rr < 16; ++rr) {
      const int qrow = (rr & 3) + 8 * (rr >> 2) + 4 * h5;  // 0..31
      const float rl = 1.0f / __shfl(l_i, qrow, 64);
      const int s = q0 + qh * 32 + qrow;
      const size_t base = ((size_t)b * Sdim + s) * Ddim + h * DH;
      ctx[base + n31] = (_Float16)(oacc0[rr] * rl);
      ctx[base + 32 + n31] = (_Float16)(oacc1[rr] * rl);
    }
  }
}

// ------------------------------ launcher -----------------------------------
extern "C" void kernel_launch(void* const* d_in, const int* in_sizes, int n_in,
                              void* d_out, int out_size, void* d_ws,
                              size_t ws_size, hipStream_t stream) {
  const float* hid = (const float*)d_in[0];
  const float* Wq = (const float*)d_in[1];
  const float* bq = (const float*)d_in[2];
  const float* Wk = (const float*)d_in[3];
  const float* bk = (const float*)d_in[4];
  const float* Wv = (const float*)d_in[5];
  const float* bv = (const float*)d_in[6];
  const float* Wo = (const float*)d_in[7];
  const float* bo = (const float*)d_in[8];

  char* ws = (char*)d_ws;
  _Float16* ctx = (_Float16*)(ws);                 // 8 MiB
  _Float16* Wqt = (_Float16*)(ws + (8ull << 20));  // 2 MiB each
  _Float16* Wkt = (_Float16*)(ws + (10ull << 20));
  _Float16* Wvt = (_Float16*)(ws + (12ull << 20));
  _Float16* Wot = (_Float16*)(ws + (14ull << 20));
  _Float16* Qb = (_Float16*)(ws + (16ull << 20));  // 8 MiB each
  _Float16* Kb = (_Float16*)(ws + (24ull << 20));
  _Float16* Vtb = (_Float16*)(ws + (32ull << 20)); // end: 40 MiB

  PrepArgs pa{Wq, Wk, Wv, Wo, Wqt, Wkt, Wvt, Wot};
  prep<<<dim3(1024), 256, 0, stream>>>(pa);

  GemmArgs g1{hid, Wqt, Wkt, Wvt, bq, bk, bv, Qb, Kb, Vtb};
  gemmT<0, 128><<<dim3(Mrows / 128, Ddim / 128, 3), 256, 0, stream>>>(g1);

  attn<<<dim3(1024), 256, 0, stream>>>(Qb, Kb, Vtb, ctx);

  GemmArgs g2{ctx, Wot, Wot, Wot, bo, bo, bo, d_out, d_out, d_out};
  gemmT<1, 64><<<dim3(Mrows / 128, Ddim / 64, 1), 256, 0, stream>>>(g2);
}

// Round 14
// 170.440 us; speedup vs baseline: 1.0390x; 1.0390x over previous
//
#include <hip/hip_runtime.h>

// ---------------------------------------------------------------------------
// v13 = exact v9 config (measured best: 171.2us) — re-sampled to confirm.
// Pipeline: prep (xcvt+wtrans fused) -> QKV gemm (Q prescaled, V transposed)
//           -> flash attn -> O gemm (128x64 tiles).
// gemmT: 32x32x16, BK=64, rule-#21 swizzle (inverse-swizzled global source +
//   swizzled read; bank conflicts 22M -> ~0, v9-measured).
// attn: 1024 blocks LPT, reg-staged K/V prefetch-before-barrier dbuf;
//   32x32x16 MFMA; 4 waves = 2(q-half) x 2(kv-half); K rows staged with kv
//   bits2<->3 swapped so S^T output regs ARE the PV A-frags (P in-register,
//   v_cvt_pkrtz); raw v_exp_f32; l via v_dot2_f32_f16.
// 32x32x16 layouts (HW-validated): A/B m|n=lane&31, k=(lane>>5)*8+j;
//   C/D col=lane&31, row=(reg&3)+8*(reg>>2)+4*(lane>>5).
// ---------------------------------------------------------------------------

typedef _Float16 f16x8 __attribute__((ext_vector_type(8)));
typedef _Float16 f16x4 __attribute__((ext_vector_type(4)));
typedef __fp16 h16x2 __attribute__((ext_vector_type(2)));  // cvt_pkrtz ret type
typedef float f32x4 __attribute__((ext_vector_type(4)));
typedef float f32x16 __attribute__((ext_vector_type(16)));

#define GLD_LDS16(g, l)                                                        \
  __builtin_amdgcn_global_load_lds(                                            \
      (__attribute__((address_space(1))) const unsigned int*)(g),              \
      (__attribute__((address_space(3))) unsigned int*)(l), 16, 0, 0)

static constexpr int Sdim = 2048;
static constexpr int Ddim = 1024;
static constexpr int NH = 16;
static constexpr int DH = 64;
static constexpr int Mrows = 4096;  // B*S

// Q prescale: 1/sqrt(64) * log2(e), so P = exp2(S') natively.
static constexpr float QSCALE = 0.125f * 1.44269504f;

// ------------------- fused prep: xcvt + weight transpose -------------------
// blocks [0,1024): wtrans of 4 weights; blocks [1024,3072): xcvt chunks.
struct PrepArgs {
  const float* X;
  _Float16* Y;
  const float *s0, *s1, *s2, *s3;
  _Float16 *d0, *d1, *d2, *d3;
};

__global__ __launch_bounds__(256) void prep(PrepArgs a) {
  __shared__ _Float16 L[64 * 72];
  const int id = blockIdx.x, t = threadIdx.x;
  if (id >= 1024) {
    size_t i = ((size_t)(id - 1024) * 256 + t) * 8;
    float4 f0 = *(const float4*)(a.X + i);
    float4 f1 = *(const float4*)(a.X + i + 4);
    alignas(16) _Float16 h[8] = {(_Float16)f0.x, (_Float16)f0.y, (_Float16)f0.z,
                                 (_Float16)f0.w, (_Float16)f1.x, (_Float16)f1.y,
                                 (_Float16)f1.z, (_Float16)f1.w};
    *(uint4*)(a.Y + i) = *(const uint4*)h;
    return;
  }
  const int z = id >> 8;
  const float* src = z == 0 ? a.s0 : z == 1 ? a.s1 : z == 2 ? a.s2 : a.s3;
  _Float16* dst = z == 0 ? a.d0 : z == 1 ? a.d1 : z == 2 ? a.d2 : a.d3;
  const int k0 = (id & 15) * 64, n0 = ((id >> 4) & 15) * 64;
#pragma unroll
  for (int i = 0; i < 4; ++i) {
    int c = i * 256 + t;  // 1024 chunks of 4 floats
    int row = c >> 4, cc = c & 15;
    float4 f = *(const float4*)&src[(size_t)(k0 + row) * Ddim + n0 + cc * 4];
    L[(cc * 4 + 0) * 72 + row] = (_Float16)f.x;
    L[(cc * 4 + 1) * 72 + row] = (_Float16)f.y;
    L[(cc * 4 + 2) * 72 + row] = (_Float16)f.z;
    L[(cc * 4 + 3) * 72 + row] = (_Float16)f.w;
  }
  __syncthreads();
#pragma unroll
  for (int i = 0; i < 2; ++i) {
    int c = i * 256 + t;  // 512 chunks of 8 halves
    int n = c >> 3, cc = c & 7;
    *(uint4*)&dst[(size_t)(n0 + n) * Ddim + k0 + cc * 8] =
        *(const uint4*)&L[n * 72 + cc * 8];
  }
}

// --------------- 128xBN GEMM (32x32x16, BK=64, swizzled LDS) ---------------
// A [M,1024] fp16, Bt [N,K=1024] fp16.
// LDS tile rows are 64 halves (128B). Slot s (16B) of row r holds global
// k-slot s^(r&7) (inverse-swizzled source); reads XOR the same term.
// MODE 0 (BN=128): +bias -> fp16; z==0 Q (xQSCALE); z==1 K; z==2 V^T.
// MODE 1 (BN=64): +bias -> fp32 [M,1024] row-major (d_out); 512 blocks.
struct GemmArgs {
  const _Float16* A;
  const _Float16 *Bt0, *Bt1, *Bt2;
  const float *b0, *b1, *b2;
  void *o0, *o1, *o2;
};

template <int MODE, int BN>
__global__ __launch_bounds__(256) void gemmT(GemmArgs g) {
  constexpr int K = 1024;
  constexpr int BK = 64;
  constexpr int WN = BN / 2;       // per-wave n extent
  constexpr int NI = WN / 32;      // 32-wide n frags per wave
  constexpr int BCH = BN * 8;      // B chunk count (16B each)
  __shared__ _Float16 As[128 * BK];
  __shared__ _Float16 Bs[BN * BK];
  const int z = blockIdx.z;
  const _Float16* A = g.A;
  const _Float16* Bt = z == 0 ? g.Bt0 : z == 1 ? g.Bt1 : g.Bt2;
  const float* bias = z == 0 ? g.b0 : z == 1 ? g.b1 : g.b2;
  void* out = z == 0 ? g.o0 : z == 1 ? g.o1 : g.o2;
  const int m0 = blockIdx.x * 128, n0 = blockIdx.y * BN;
  const int t = threadIdx.x, lane = t & 63, wv = t >> 6;
  const int wm = wv >> 1, wn = wv & 1;
  const int n31 = lane & 31, h5 = lane >> 5, h8 = h5 * 8;

  // staging chunk c -> row c>>3, LDS slot c&7 (linear, c*16B); global k-slot
  // = (c&7) ^ (row&7)  [inverse swizzle at the source, rule #21].
  const _Float16* ga[4];
  const _Float16* gb[4];
  char* lA[4];
  char* lB[4];
#pragma unroll
  for (int i = 0; i < 4; ++i) {
    const int c = i * 256 + t, row = c >> 3;
    ga[i] = A + (size_t)(m0 + row) * K + (((c & 7) ^ (row & 7)) * 8);
    lA[i] = (char*)As + (i * 256 + wv * 64) * 16;
  }
#pragma unroll
  for (int i = 0; i < BCH / 256; ++i) {
    const int c = i * 256 + t, row = c >> 3;
    gb[i] = Bt + (size_t)(n0 + row) * K + (((c & 7) ^ (row & 7)) * 8);
    lB[i] = (char*)Bs + (i * 256 + wv * 64) * 16;
  }
  const int rsw = (n31 & 7) << 3;  // read swizzle (all frag rows have &7==n31&7)

  f32x16 acc[2][NI] = {};
  for (int kt = 0; kt < K; kt += BK) {
#pragma unroll
    for (int i = 0; i < 4; ++i) GLD_LDS16(ga[i] + kt, lA[i]);
#pragma unroll
    for (int i = 0; i < BCH / 256; ++i) GLD_LDS16(gb[i] + kt, lB[i]);
    __syncthreads();
#pragma unroll
    for (int ks = 0; ks < 4; ++ks) {
      const int kc = (ks * 16 + h8) ^ rsw;
      f16x8 a0 = *(const f16x8*)&As[(wm * 64 + n31) * BK + kc];
      f16x8 a1 = *(const f16x8*)&As[(wm * 64 + 32 + n31) * BK + kc];
#pragma unroll
      for (int ni = 0; ni < NI; ++ni) {
        f16x8 bf = *(const f16x8*)&Bs[(wn * WN + ni * 32 + n31) * BK + kc];
        acc[0][ni] =
            __builtin_amdgcn_mfma_f32_32x32x16_f16(a0, bf, acc[0][ni], 0, 0, 0);
        acc[1][ni] =
            __builtin_amdgcn_mfma_f32_32x32x16_f16(a1, bf, acc[1][ni], 0, 0, 0);
      }
    }
    __syncthreads();
  }

  const float scale = (MODE == 0 && z == 0) ? QSCALE : 1.0f;
  float bv[NI];
#pragma unroll
  for (int ni = 0; ni < NI; ++ni) bv[ni] = bias[n0 + wn * WN + ni * 32 + n31];
#pragma unroll
  for (int mi = 0; mi < 2; ++mi) {
#pragma unroll
    for (int ni = 0; ni < NI; ++ni) {
      const int n = n0 + wn * WN + ni * 32 + n31;
      if (MODE == 0 && z == 2) {
        // V^T store: rows (reg&3) consecutive in s -> uint2 of 4 halves
        const int b = (m0 >> 11), h = n >> 6, dh = n & 63;
#pragma unroll
        for (int hi = 0; hi < 4; ++hi) {
          alignas(8) _Float16 h4[4];
#pragma unroll
          for (int j = 0; j < 4; ++j)
            h4[j] = (_Float16)(acc[mi][ni][hi * 4 + j] + bv[ni]);
          const int m = m0 + wm * 64 + mi * 32 + 8 * hi + 4 * h5;
          const int s = m & 2047;
          *(uint2*)&(
              (_Float16*)out)[((size_t)(b * NH + h) * DH + dh) * Sdim + s] =
              *(const uint2*)h4;
        }
      } else {
#pragma unroll
        for (int rr = 0; rr < 16; ++rr) {
          const int m =
              m0 + wm * 64 + mi * 32 + (rr & 3) + 8 * (rr >> 2) + 4 * h5;
          const float v = (acc[mi][ni][rr] + bv[ni]) * scale;
          if (MODE == 0) {
            const int b = m >> 11, s = m & 2047, h = n >> 6, dh = n & 63;
            ((_Float16*)out)[(((size_t)(b * NH + h) * Sdim + s) << 6) + dh] =
                (_Float16)v;
          } else {
            ((float*)out)[(size_t)m * Ddim + n] = v;
          }
        }
      }
    }
  }
}

// ------------------------- flash attention (v9) ----------------------------
// 1024 blocks x 256 thr; block = one 64-q tile; LPT descending; bh XCD-local
// (4 blocks/CU resident -> TLP hides the serial tile chain). Reg-staged K/V
// with prefetch-before-barrier + ds_write double-buffer.
// K rows LDS-permuted (swap bits 2,3) so S^T C/D regs feed PV A-frags
// directly (P fully in-register). LDS [64][64] tiles, XOR-swizzle (row&7)<<3.
__global__ __launch_bounds__(256) void attn(const _Float16* __restrict__ Q,
                                            const _Float16* __restrict__ Kk,
                                            const _Float16* __restrict__ Vt,
                                            _Float16* __restrict__ ctx) {
  __shared__ _Float16 Ks[2][64 * 64], Vs[2][64 * 64];
  const int id = blockIdx.x, xcd = id & 7, slot = id >> 3;
  const int qt = 31 - (slot >> 2);           // descending work (LPT)
  const int bh = ((slot & 3) << 3) | xcd;    // 4 bh per xcd
  const int q0 = qt * 64;
  const int t = threadIdx.x, lane = t & 63, wv = t >> 6;
  const int qh = wv & 1, kvh = wv >> 1;
  const int n31 = lane & 31, h5 = lane >> 5, h8 = h5 * 8;
  const int b = bh >> 4, h = bh & 15;
  const _Float16* Kg = Kk + (size_t)bh * Sdim * DH;
  const _Float16* Vg = Vt + (size_t)bh * DH * Sdim;  // [64 dh, S]

  const int qg = q0 + qh * 32 + n31;  // lane's q column (S^T col)
  const _Float16* Qrow = Q + ((size_t)bh * Sdim + qg) * DH;
  f16x8 aq[4];
#pragma unroll
  for (int ks = 0; ks < 4; ++ks) aq[ks] = *(const f16x8*)(Qrow + ks * 16 + h8);

  const int ntiles = qt + 1;
  // staging: thread covers rows sr, sr+32 (16B chunk each) for K and V
  const int sr = t >> 3, sr2 = sr + 32, sc = (t & 7) * 8;
  // K rows permuted: swap bits 2,3 (kv-contraction relabel; V cols natural)
  const int kr = (sr & 51) | ((sr & 4) << 1) | ((sr & 8) >> 1);
  const int kr2 = (sr2 & 51) | ((sr2 & 4) << 1) | ((sr2 & 8) >> 1);
  const int kc = sc ^ ((kr & 7) << 3), kc2 = sc ^ ((kr2 & 7) << 3);
  const int vc = sc ^ ((sr & 7) << 3), vc2 = sc ^ ((sr2 & 7) << 3);

  f32x16 oacc0 = {}, oacc1 = {};
  float l_i = 0.f;
  const h16x2 one2 = {(__fp16)1.0f, (__fp16)1.0f};

  // prologue: stage tile 0 into buf 0
  uint4 ka = *(const uint4*)&Kg[(size_t)sr * DH + sc];
  uint4 kb = *(const uint4*)&Kg[(size_t)sr2 * DH + sc];
  uint4 va = *(const uint4*)&Vg[(size_t)sr * Sdim + sc];
  uint4 vb = *(const uint4*)&Vg[(size_t)sr2 * Sdim + sc];
  *(uint4*)&Ks[0][kr * 64 + kc] = ka;
  *(uint4*)&Ks[0][kr2 * 64 + kc2] = kb;
  *(uint4*)&Vs[0][sr * 64 + vc] = va;
  *(uint4*)&Vs[0][sr2 * 64 + vc2] = vb;

  const int prow = kvh * 32 + n31;            // Ks read row for S-phase
  const int pb = prow * 64, psw = (prow & 7) << 3;
  const int vsw = (n31 & 7) << 3;             // Vs read swizzle

  for (int it = 0; it < ntiles; ++it) {
    const int cur = it & 1;
    if (it + 1 < ntiles) {  // prefetch next tile into regs (T14: issue early)
      const int kvn = (it + 1) * 64;
      ka = *(const uint4*)&Kg[(size_t)(kvn + sr) * DH + sc];
      kb = *(const uint4*)&Kg[(size_t)(kvn + sr2) * DH + sc];
      va = *(const uint4*)&Vg[(size_t)sr * Sdim + kvn + sc];
      vb = *(const uint4*)&Vg[(size_t)sr2 * Sdim + kvn + sc];
    }
    __syncthreads();  // buf[cur] fully staged

    // S^T = K Q^T over the wave's 32-kv half (single acc chain)
    f32x16 sacc = {};
    __builtin_amdgcn_s_setprio(1);
#pragma unroll
    for (int ks = 0; ks < 4; ++ks) {
      f16x8 ak = *(const f16x8*)&Ks[cur][pb + ((ks * 16 + h8) ^ psw)];
      sacc = __builtin_amdgcn_mfma_f32_32x32x16_f16(ak, aq[ks], sacc, 0, 0, 0);
    }
    __builtin_amdgcn_s_setprio(0);

    // mask (diag tile only; wave-uniform branch)
    const int kvb = it * 64;
    if (it == ntiles - 1) {
#pragma unroll
      for (int i = 0; i < 16; ++i) {
        const int kvgl = kvb + kvh * 32 + (i & 7) + h8 + 16 * (i >> 3);
        if (kvgl > qg) sacc[i] = -1e30f;
      }
    }
    // P = exp2 (raw v_exp_f32), pack to f16 pairs, l via v_dot2_f32_f16
    union U { f16x8 v8; h16x2 v2[4]; } u0, u1;
#pragma unroll
    for (int i = 0; i < 4; ++i) {
      const float p0 = __builtin_amdgcn_exp2f(sacc[2 * i]);
      const float p1 = __builtin_amdgcn_exp2f(sacc[2 * i + 1]);
      u0.v2[i] = __builtin_amdgcn_cvt_pkrtz(p0, p1);
      l_i = __builtin_amdgcn_fdot2(u0.v2[i], one2, l_i, false);
    }
#pragma unroll
    for (int i = 0; i < 4; ++i) {
      const float p0 = __builtin_amdgcn_exp2f(sacc[8 + 2 * i]);
      const float p1 = __builtin_amdgcn_exp2f(sacc[9 + 2 * i]);
      u1.v2[i] = __builtin_amdgcn_cvt_pkrtz(p0, p1);
      l_i = __builtin_amdgcn_fdot2(u1.v2[i], one2, l_i, false);
    }

    // O += P V over the wave's kv half: B = V^T rows (n = dh)
    __builtin_amdgcn_s_setprio(1);
#pragma unroll
    for (int ks = 0; ks < 2; ++ks) {
      const f16x8 ap = ks ? u1.v8 : u0.v8;
      const int col = kvh * 32 + ks * 16 + h8;
      f16x8 bv0 = *(const f16x8*)&Vs[cur][n31 * 64 + (col ^ vsw)];
      f16x8 bv1 = *(const f16x8*)&Vs[cur][(32 + n31) * 64 + (col ^ vsw)];
      oacc0 = __builtin_amdgcn_mfma_f32_32x32x16_f16(ap, bv0, oacc0, 0, 0, 0);
      oacc1 = __builtin_amdgcn_mfma_f32_32x32x16_f16(ap, bv1, oacc1, 0, 0, 0);
    }
    __builtin_amdgcn_s_setprio(0);

    if (it + 1 < ntiles) {  // write prefetched regs into other buffer
      const int nxt = cur ^ 1;
      *(uint4*)&Ks[nxt][kr * 64 + kc] = ka;
      *(uint4*)&Ks[nxt][kr2 * 64 + kc2] = kb;
      *(uint4*)&Vs[nxt][sr * 64 + vc] = va;
      *(uint4*)&Vs[nxt][sr2 * 64 + vc2] = vb;
    }
  }

  // ---- cross-wave kv-half reduction (once per block) ----
  l_i += __shfl_xor(l_i, 32, 64);  // full sum over this wave's kv half
  __syncthreads();                 // all KV LDS reads done; reuse as scratch
  float* obuf = (float*)&Ks[0][0] + qh * (64 * 32);  // 8KB per q-half
  float* lbuf = (float*)&Vs[0][0] + qh * 64;
  union V16 { f32x16 v; f32x4 q[4]; };
  if (kvh == 1) {
    V16 a, c;
    a.v = oacc0;
    c.v = oacc1;
#pragma unroll
    for (int k = 0; k < 4; ++k) {
      *(f32x4*)&obuf[lane * 32 + ((k ^ (lane & 7)) << 2)] = a.q[k];
      *(f32x4*)&obuf[lane * 32 + (((k + 4) ^ (lane & 7)) << 2)] = c.q[k];
    }
    lbuf[lane] = l_i;
  }
  __syncthreads();
  if (kvh == 0) {
    V16 a, c;
#pragma unroll
    for (int k = 0; k < 4; ++k) {
      a.q[k] = *(const f32x4*)&obuf[lane * 32 + ((k ^ (lane & 7)) << 2)];
      c.q[k] = *(const f32x4*)&obuf[lane * 32 + (((k + 4) ^ (lane & 7)) << 2)];
    }
    oacc0 += a.v;
    oacc1 += c.v;
    l_i += lbuf[lane];
    // epilogue: row q = (rr&3)+8*(rr>>2)+4*h5; col dh = n31 (+32)
#pragma unroll
    for (int rr = 0; rr < 16; ++rr) {
      const int qrow = (rr & 3) + 8 * (rr >> 2) + 4 * h5;  // 0..31
      const float rl = 1.0f / __shfl(l_i, qrow, 64);
      const int s = q0 + qh * 32 + qrow;
      const size_t base = ((size_t)b * Sdim + s) * Ddim + h * DH;
      ctx[base + n31] = (_Float16)(oacc0[rr] * rl);
      ctx[base + 32 + n31] = (_Float16)(oacc1[rr] * rl);
    }
  }
}

// ------------------------------ launcher -----------------------------------
extern "C" void kernel_launch(void* const* d_in, const int* in_sizes, int n_in,
                              void* d_out, int out_size, void* d_ws,
                              size_t ws_size, hipStream_t stream) {
  const float* hid = (const float*)d_in[0];
  const float* Wq = (const float*)d_in[1];
  const float* bq = (const float*)d_in[2];
  const float* Wk = (const float*)d_in[3];
  const float* bk = (const float*)d_in[4];
  const float* Wv = (const float*)d_in[5];
  const float* bv = (const float*)d_in[6];
  const float* Wo = (const float*)d_in[7];
  const float* bo = (const float*)d_in[8];

  char* ws = (char*)d_ws;
  _Float16* Xh = (_Float16*)(ws);                  // 8 MiB (reused as ctx)
  _Float16* Wqt = (_Float16*)(ws + (8ull << 20));  // 2 MiB each
  _Float16* Wkt = (_Float16*)(ws + (10ull << 20));
  _Float16* Wvt = (_Float16*)(ws + (12ull << 20));
  _Float16* Wot = (_Float16*)(ws + (14ull << 20));
  _Float16* Qb = (_Float16*)(ws + (16ull << 20));  // 8 MiB each
  _Float16* Kb = (_Float16*)(ws + (24ull << 20));
  _Float16* Vtb = (_Float16*)(ws + (32ull << 20)); // end: 40 MiB
  _Float16* ctx = Xh;

  PrepArgs pa{hid, Xh, Wq, Wk, Wv, Wo, Wqt, Wkt, Wvt, Wot};
  prep<<<dim3(3072), 256, 0, stream>>>(pa);

  GemmArgs g1{Xh, Wqt, Wkt, Wvt, bq, bk, bv, Qb, Kb, Vtb};
  gemmT<0, 128><<<dim3(Mrows / 128, Ddim / 128, 3), 256, 0, stream>>>(g1);

  attn<<<dim3(1024), 256, 0, stream>>>(Qb, Kb, Vtb, ctx);

  GemmArgs g2{ctx, Wot, Wot, Wot, bo, bo, bo, d_out, d_out, d_out};
  gemmT<1, 64><<<dim3(Mrows / 128, Ddim / 64, 1), 256, 0, stream>>>(g2);
}